// Round 1
// baseline (8001.438 us; speedup 1.0000x reference)
//
#include <hip/hip_runtime.h>

#define BB 128
#define CH 16
#define EE 10
#define FF 10
#define GG 9
#define HH 9
#define SP (EE*FF*GG*HH)   /* 8100 */
#define GHS (GG*HH)        /* 81 */
#define NBANDS 100
#define OUTC 10

// ---------------- prep: local = x - center, layout [b][1][e][f][g][h] ----------------
__global__ void prep_kernel(const float* __restrict__ x, float* __restrict__ out, int nb) {
    int idx = blockIdx.x * 256 + threadIdx.x;
    int total = nb * NBANDS * GHS;
    if (idx >= total) return;
    int s = idx % GHS;
    int p = (idx / GHS) % NBANDS;
    int b = idx / (GHS * NBANDS);
    const float* xp = x + ((size_t)b * NBANDS + p) * GHS;
    out[idx] = xp[s] - xp[40];   // center = (4,4) -> 4*9+4
}

// ---------------- generic 4D conv + bias + relu ----------------
// in : [b][CIN][e][f][g][h], w : [16][CIN][3][3][3][3], out : [b][16][e][f][g][h]
template<int CIN>
__global__ __launch_bounds__(256) void conv4d_kernel(
    const float* __restrict__ in, const float* __restrict__ w,
    const float* __restrict__ bias, float* __restrict__ out) {

    int s   = blockIdx.x * 256 + threadIdx.x;   // spatial linear index
    int co0 = blockIdx.y * 4;                   // 4 output channels per thread
    int b   = blockIdx.z;
    bool active = (s < SP);
    int ss = active ? s : 0;

    int h = ss % 9;
    int g = (ss / 9) % 9;
    int f = (ss / 81) % 10;
    int e = ss / 810;

    float acc0 = bias[co0 + 0];
    float acc1 = bias[co0 + 1];
    float acc2 = bias[co0 + 2];
    float acc3 = bias[co0 + 3];

    #pragma unroll 1
    for (int ci = 0; ci < CIN; ++ci) {
        const float* ip = in + ((size_t)b * CIN + ci) * SP;
        const float* wp = w + ((size_t)co0 * CIN + ci) * 81;
        #pragma unroll
        for (int de = 0; de < 3; ++de) {
            int e2 = e + de - 1;
            if ((unsigned)e2 >= EE) continue;
            #pragma unroll
            for (int df = 0; df < 3; ++df) {
                int f2 = f + df - 1;
                if ((unsigned)f2 >= FF) continue;
                const float* ip2 = ip + (e2 * 10 + f2) * 81;
                const float* wp2 = wp + (de * 3 + df) * 9;
                #pragma unroll
                for (int dg = 0; dg < 3; ++dg) {
                    int g2 = g + dg - 1;
                    if ((unsigned)g2 >= GG) continue;
                    #pragma unroll
                    for (int dh = 0; dh < 3; ++dh) {
                        int h2 = h + dh - 1;
                        if ((unsigned)h2 >= HH) continue;
                        float v = ip2[g2 * 9 + h2];
                        int t = dg * 3 + dh;
                        acc0 += wp2[0 * CIN * 81 + t] * v;
                        acc1 += wp2[1 * CIN * 81 + t] * v;
                        acc2 += wp2[2 * CIN * 81 + t] * v;
                        acc3 += wp2[3 * CIN * 81 + t] * v;
                    }
                }
            }
        }
    }

    if (active) {
        float* op = out + ((size_t)b * CH + co0) * SP + s;
        op[0 * SP] = fmaxf(acc0, 0.f);
        op[1 * SP] = fmaxf(acc1, 0.f);
        op[2 * SP] = fmaxf(acc2, 0.f);
        op[3 * SP] = fmaxf(acc3, 0.f);
    }
}

// ---------------- feat = mean over (e,f): [b][c][gh] ----------------
__global__ void feat_kernel(const float* __restrict__ a, float* __restrict__ feat, int nb) {
    int idx = blockIdx.x * 256 + threadIdx.x;
    if (idx >= nb * CH * GHS) return;
    int s = idx % GHS;
    int c = (idx / GHS) % CH;
    int b = idx / (GHS * CH);
    const float* ap = a + ((size_t)b * CH + c) * SP + s;
    float sum = 0.f;
    #pragma unroll
    for (int ef = 0; ef < 100; ++ef) sum += ap[ef * GHS];
    feat[idx] = sum * 0.01f;
}

// ---------------- fc: out[b][o][gh] ----------------
__global__ void fc_kernel(const float* __restrict__ feat, const float* __restrict__ fcw,
                          const float* __restrict__ fcb, float* __restrict__ out, int nb) {
    int idx = blockIdx.x * 256 + threadIdx.x;
    if (idx >= nb * OUTC * GHS) return;
    int s = idx % GHS;
    int o = (idx / GHS) % OUTC;
    int b = idx / (GHS * OUTC);
    const float* fp = feat + (size_t)b * CH * GHS + s;
    float acc = fcb[o];
    #pragma unroll
    for (int c = 0; c < CH; ++c) acc += fcw[o * CH + c] * fp[c * GHS];
    out[idx] = acc;
}

extern "C" void kernel_launch(void* const* d_in, const int* in_sizes, int n_in,
                              void* d_out, int out_size, void* d_ws, size_t ws_size,
                              hipStream_t stream) {
    const float* x   = (const float*)d_in[0];
    const float* w1  = (const float*)d_in[1];
    const float* b1  = (const float*)d_in[2];
    const float* w2  = (const float*)d_in[3];
    const float* b2  = (const float*)d_in[4];
    const float* w3  = (const float*)d_in[5];
    const float* b3  = (const float*)d_in[6];
    const float* w4  = (const float*)d_in[7];
    const float* b4  = (const float*)d_in[8];
    const float* w5  = (const float*)d_in[9];
    const float* b5  = (const float*)d_in[10];
    const float* fcw = (const float*)d_in[11];
    const float* fcb = (const float*)d_in[12];
    float* outp = (float*)d_out;

    // per-b floats for two ping-pong buffers
    const size_t perb_floats = 2ull * CH * SP;           // 259200 floats
    int nbmax = (int)(ws_size / (perb_floats * 4));
    if (nbmax < 1)  nbmax = 1;
    if (nbmax > BB) nbmax = BB;

    float* bufA = (float*)d_ws;
    float* bufB = bufA + (size_t)nbmax * CH * SP;

    for (int b0 = 0; b0 < BB; b0 += nbmax) {
        int nb = BB - b0;
        if (nb > nbmax) nb = nbmax;

        int prep_total = nb * NBANDS * GHS;
        prep_kernel<<<(prep_total + 255) / 256, 256, 0, stream>>>(x + (size_t)b0 * NBANDS * GHS, bufA, nb);

        dim3 cg(32, 4, nb);
        conv4d_kernel<1><<<cg, 256, 0, stream>>>(bufA, w1, b1, bufB);
        conv4d_kernel<16><<<cg, 256, 0, stream>>>(bufB, w2, b2, bufA);
        conv4d_kernel<16><<<cg, 256, 0, stream>>>(bufA, w3, b3, bufB);
        conv4d_kernel<16><<<cg, 256, 0, stream>>>(bufB, w4, b4, bufA);
        conv4d_kernel<16><<<cg, 256, 0, stream>>>(bufA, w5, b5, bufB);

        int ft = nb * CH * GHS;
        feat_kernel<<<(ft + 255) / 256, 256, 0, stream>>>(bufB, bufA, nb);

        int ot = nb * OUTC * GHS;
        fc_kernel<<<(ot + 255) / 256, 256, 0, stream>>>(bufA, fcw, fcb, outp + (size_t)b0 * OUTC * GHS, nb);
    }
}

// Round 2
// 1894.455 us; speedup vs baseline: 4.2236x; 4.2236x over previous
//
#include <hip/hip_runtime.h>

#define BB 128
#define CH 16
#define EE 10
#define FF 10
#define GG 9
#define HH 9
#define SP (EE*FF*GG*HH)   /* 8100 */
#define GHS (GG*HH)        /* 81 */
#define EFG (EE*FF*GG)     /* 900 */
#define NBANDS 100
#define OUTC 10

// ---------------- prep: local = x - center, layout [b][1][e][f][g][h] ----------------
__global__ void prep_kernel(const float* __restrict__ x, float* __restrict__ out, int nb) {
    int idx = blockIdx.x * 256 + threadIdx.x;
    int total = nb * NBANDS * GHS;
    if (idx >= total) return;
    int s = idx % GHS;
    int p = (idx / GHS) % NBANDS;
    int b = idx / (GHS * NBANDS);
    const float* xp = x + ((size_t)b * NBANDS + p) * GHS;
    out[idx] = xp[s] - xp[40];   // center = (4,4) -> 4*9+4
}

// ---------------- 4D conv + bias + relu, h-register-blocked ----------------
// in : [b][CIN][e][f][g][h], w : [16][CIN][3][3][3][3], out : [b][16][e][f][g][h]
// thread = (b, co-group of 8, e, f, g); computes all 9 h outputs for 8 co.
template<int CIN>
__global__ __launch_bounds__(256) void conv4d_kernel(
    const float* __restrict__ in, const float* __restrict__ w,
    const float* __restrict__ bias, float* __restrict__ out) {

    int idx = blockIdx.x * 256 + threadIdx.x;   // over e*f*g = 900
    if (idx >= EFG) return;
    int b   = blockIdx.z;
    int co0 = blockIdx.y * 8;

    int g = idx % 9;
    int f = (idx / 9) % 10;
    int e = idx / 90;

    float acc[8][9];
    #pragma unroll
    for (int co = 0; co < 8; ++co) {
        float bv = bias[co0 + co];
        #pragma unroll
        for (int h = 0; h < 9; ++h) acc[co][h] = bv;
    }

    const float* inb = in + (size_t)b * CIN * SP;
    const float* wb  = w + (size_t)co0 * CIN * 81;

    #pragma unroll 1
    for (int ci = 0; ci < CIN; ++ci) {
        const float* ip = inb + ci * SP;
        const float* wp = wb + ci * 81;
        #pragma unroll
        for (int de = 0; de < 3; ++de) {
            int e2 = e + de - 1;
            if ((unsigned)e2 >= EE) continue;
            #pragma unroll
            for (int df = 0; df < 3; ++df) {
                int f2 = f + df - 1;
                if ((unsigned)f2 >= FF) continue;
                const float* ip2 = ip + (e2 * 10 + f2) * 81;
                const float* wp2 = wp + (de * 3 + df) * 9;
                #pragma unroll
                for (int dg = 0; dg < 3; ++dg) {
                    int g2 = g + dg - 1;
                    if ((unsigned)g2 >= GG) continue;
                    // load one 9-float input row, reuse for 3 dh shifts x 8 co
                    const float* rp = ip2 + g2 * 9;
                    float v[9];
                    #pragma unroll
                    for (int h = 0; h < 9; ++h) v[h] = rp[h];
                    #pragma unroll
                    for (int dh = 0; dh < 3; ++dh) {
                        #pragma unroll
                        for (int co = 0; co < 8; ++co) {
                            float ws = wp2[co * (CIN * 81) + dg * 3 + dh];
                            #pragma unroll
                            for (int h = 0; h < 9; ++h) {
                                int h2 = h + dh - 1;      // compile-time resolved bounds
                                if (h2 < 0 || h2 > 8) continue;
                                acc[co][h] = fmaf(ws, v[h2], acc[co][h]);
                            }
                        }
                    }
                }
            }
        }
    }

    float* op = out + ((size_t)b * CH + co0) * SP + (e * 10 + f) * 81 + g * 9;
    #pragma unroll
    for (int co = 0; co < 8; ++co) {
        #pragma unroll
        for (int h = 0; h < 9; ++h)
            op[co * SP + h] = fmaxf(acc[co][h], 0.f);
    }
}

// ---------------- feat = mean over (e,f): [b][c][gh] ----------------
__global__ void feat_kernel(const float* __restrict__ a, float* __restrict__ feat, int nb) {
    int idx = blockIdx.x * 256 + threadIdx.x;
    if (idx >= nb * CH * GHS) return;
    int s = idx % GHS;
    int c = (idx / GHS) % CH;
    int b = idx / (GHS * CH);
    const float* ap = a + ((size_t)b * CH + c) * SP + s;
    float sum = 0.f;
    #pragma unroll
    for (int ef = 0; ef < 100; ++ef) sum += ap[ef * GHS];
    feat[idx] = sum * 0.01f;
}

// ---------------- fc: out[b][o][gh] ----------------
__global__ void fc_kernel(const float* __restrict__ feat, const float* __restrict__ fcw,
                          const float* __restrict__ fcb, float* __restrict__ out, int nb) {
    int idx = blockIdx.x * 256 + threadIdx.x;
    if (idx >= nb * OUTC * GHS) return;
    int s = idx % GHS;
    int o = (idx / GHS) % OUTC;
    int b = idx / (GHS * OUTC);
    const float* fp = feat + (size_t)b * CH * GHS + s;
    float acc = fcb[o];
    #pragma unroll
    for (int c = 0; c < CH; ++c) acc += fcw[o * CH + c] * fp[c * GHS];
    out[idx] = acc;
}

extern "C" void kernel_launch(void* const* d_in, const int* in_sizes, int n_in,
                              void* d_out, int out_size, void* d_ws, size_t ws_size,
                              hipStream_t stream) {
    const float* x   = (const float*)d_in[0];
    const float* w1  = (const float*)d_in[1];
    const float* b1  = (const float*)d_in[2];
    const float* w2  = (const float*)d_in[3];
    const float* b2  = (const float*)d_in[4];
    const float* w3  = (const float*)d_in[5];
    const float* b3  = (const float*)d_in[6];
    const float* w4  = (const float*)d_in[7];
    const float* b4  = (const float*)d_in[8];
    const float* w5  = (const float*)d_in[9];
    const float* b5  = (const float*)d_in[10];
    const float* fcw = (const float*)d_in[11];
    const float* fcb = (const float*)d_in[12];
    float* outp = (float*)d_out;

    // per-b floats for two ping-pong buffers
    const size_t perb_floats = 2ull * CH * SP;           // 259200 floats
    int nbmax = (int)(ws_size / (perb_floats * 4));
    if (nbmax < 1)  nbmax = 1;
    if (nbmax > BB) nbmax = BB;

    float* bufA = (float*)d_ws;
    float* bufB = bufA + (size_t)nbmax * CH * SP;

    for (int b0 = 0; b0 < BB; b0 += nbmax) {
        int nb = BB - b0;
        if (nb > nbmax) nb = nbmax;

        int prep_total = nb * NBANDS * GHS;
        prep_kernel<<<(prep_total + 255) / 256, 256, 0, stream>>>(x + (size_t)b0 * NBANDS * GHS, bufA, nb);

        dim3 cg((EFG + 255) / 256, 2, nb);   // (4, 2, nb)
        conv4d_kernel<1><<<cg, 256, 0, stream>>>(bufA, w1, b1, bufB);
        conv4d_kernel<16><<<cg, 256, 0, stream>>>(bufB, w2, b2, bufA);
        conv4d_kernel<16><<<cg, 256, 0, stream>>>(bufA, w3, b3, bufB);
        conv4d_kernel<16><<<cg, 256, 0, stream>>>(bufB, w4, b4, bufA);
        conv4d_kernel<16><<<cg, 256, 0, stream>>>(bufA, w5, b5, bufB);

        int ft = nb * CH * GHS;
        feat_kernel<<<(ft + 255) / 256, 256, 0, stream>>>(bufB, bufA, nb);

        int ot = nb * OUTC * GHS;
        fc_kernel<<<(ot + 255) / 256, 256, 0, stream>>>(bufA, fcw, fcb, outp + (size_t)b0 * OUTC * GHS, nb);
    }
}

// Round 3
// 858.093 us; speedup vs baseline: 9.3247x; 2.2077x over previous
//
#include <hip/hip_runtime.h>

#define BB 128
#define CH 16
#define NBANDS 100
#define OUTC 10

// padded activation geometry: e' in [0,12), f' in [0,12), g' in [0,11), h' in [0,11)
#define E2 12
#define F2 12
#define G2 11
#define H2 11
#define PPLANE (G2*H2)        /* 121 */
#define PPOS (E2*F2*PPLANE)   /* 17424 */
#define NPAIR 41              /* 81 taps -> 40 pairs + 1 (zero-padded) */
#define WPL (NPAIR*64*8)      /* packed ushorts per layer */

typedef unsigned short ushort_t;
typedef unsigned int uint_t;
typedef __attribute__((ext_vector_type(8))) short short8;
typedef __attribute__((ext_vector_type(4))) float f32x4;

__device__ __forceinline__ ushort_t f2bf(float f) {
    unsigned u = __float_as_uint(f);
    unsigned r = u + 0x7fffu + ((u >> 16) & 1u);   // RNE
    return (ushort_t)(r >> 16);
}
__device__ __forceinline__ uint_t pk2(float a, float b) {
    return (uint_t)f2bf(a) | ((uint_t)f2bf(b) << 16);
}
__device__ __forceinline__ int swz(int x) { return x ^ ((x >> 3) & 0x30); }

// ---------------- prep: local = x - center, into padded single-channel fp32 ----------------
__global__ void prep_kernel(const float* __restrict__ x, float* __restrict__ bufP, int nb) {
    int idx = blockIdx.x * 256 + threadIdx.x;
    if (idx >= nb * NBANDS * 81) return;
    int s = idx % 81;
    int p = (idx / 81) % NBANDS;
    int b = idx / (81 * NBANDS);
    int e = p / 10, f = p % 10, g = s / 9, h = s % 9;
    const float* xp = x + ((size_t)b * NBANDS + p) * 81;
    float v = xp[s] - xp[40];
    bufP[(size_t)b * PPOS + ((e + 1) * F2 + (f + 1)) * PPLANE + (g + 1) * H2 + (h + 1)] = v;
}

// ---------------- pack weights for MFMA B-fragment ----------------
// w: [16 co][16 ci][81 tap] fp32 -> wp: [41 pair][64 lane] uint4 (8 bf16)
__global__ void pack_w_kernel(const float* __restrict__ w, uint4* __restrict__ wp) {
    int t = blockIdx.x * 256 + threadIdx.x;
    if (t >= NPAIR * 64) return;
    int pair = t >> 6, l = t & 63;
    int co = l & 15, kh = l >> 4;
    int tap = pair * 2 + (kh >> 1);
    int cib = (kh & 1) * 8;
    uint_t r[4];
    #pragma unroll
    for (int jj = 0; jj < 4; ++jj) {
        ushort_t lo = 0, hi = 0;
        if (tap < 81) {
            lo = f2bf(w[(co * 16 + cib + 2 * jj) * 81 + tap]);
            hi = f2bf(w[(co * 16 + cib + 2 * jj + 1) * 81 + tap]);
        }
        r[jj] = (uint_t)lo | ((uint_t)hi << 16);
    }
    uint4 q; q.x = r[0]; q.y = r[1]; q.z = r[2]; q.w = r[3];
    wp[t] = q;
}

// ---------------- L1: cin=1 fp32 conv on padded buffers ----------------
__global__ __launch_bounds__(256) void conv1_kernel(
    const float* __restrict__ in, const float* __restrict__ w,
    const float* __restrict__ bias, float* __restrict__ out) {
    int idx = blockIdx.x * 256 + threadIdx.x;   // over e*f*g = 900
    if (idx >= 900) return;
    int b = blockIdx.z;
    int co0 = blockIdx.y * 8;
    int g = idx % 9;
    int f = (idx / 9) % 10;
    int e = idx / 90;

    float acc[8][9];
    #pragma unroll
    for (int co = 0; co < 8; ++co) {
        float bv = bias[co0 + co];
        #pragma unroll
        for (int h = 0; h < 9; ++h) acc[co][h] = bv;
    }

    const float* ip = in + (size_t)b * PPOS;
    #pragma unroll
    for (int de = 0; de < 3; ++de)
    #pragma unroll
    for (int df = 0; df < 3; ++df)
    #pragma unroll
    for (int dg = 0; dg < 3; ++dg) {
        const float* rp = ip + ((e + de) * F2 + (f + df)) * PPLANE + (g + dg) * H2;
        float v[11];
        #pragma unroll
        for (int k = 0; k < 11; ++k) v[k] = rp[k];
        #pragma unroll
        for (int dh = 0; dh < 3; ++dh) {
            int tap = de * 27 + df * 9 + dg * 3 + dh;
            #pragma unroll
            for (int co = 0; co < 8; ++co) {
                float ws = w[(co0 + co) * 81 + tap];
                #pragma unroll
                for (int h = 0; h < 9; ++h)
                    acc[co][h] = fmaf(ws, v[h + dh], acc[co][h]);
            }
        }
    }

    float* op = out + ((size_t)b * PPOS + ((e + 1) * F2 + (f + 1)) * PPLANE + (g + 1) * H2 + 1) * 16;
    #pragma unroll
    for (int co = 0; co < 8; ++co)
        #pragma unroll
        for (int h = 0; h < 9; ++h)
            op[h * 16 + co0 + co] = fmaxf(acc[co][h], 0.f);
}

// ---------------- MFMA conv: 16 ci -> 16 co, tap-pair GEMMs ----------------
// in/out: padded fp32 [b][17424][16]; wp: packed bf16 B-frags [41][64] uint4
__global__ __launch_bounds__(512, 4) void conv_mfma_kernel(
    const float* __restrict__ in, const uint4* __restrict__ wp,
    const float* __restrict__ bias, float* __restrict__ out) {

    __shared__ __align__(16) ushort_t sIn[16 * PPLANE * 16];  // 61952 B, bf16, swizzled
    char* sInB = (char*)sIn;

    int tid = threadIdx.x;
    int b = blockIdx.y;
    int te = blockIdx.x / 5, tf = blockIdx.x % 5;
    int e0 = te * 2, f0 = tf * 2;

    // ---- stage input tile: planes (e0+pe, f0+pf), pe,pf in [0,4), fp32->bf16 ----
    const float* gin = in + (size_t)b * PPOS * 16;
    for (int i = tid; i < 16 * PPLANE; i += 512) {
        int plane = i / PPLANE, p = i - plane * PPLANE;
        int pe = plane >> 2, pf = plane & 3;
        const float4* g4 = (const float4*)(gin + (size_t)(((e0 + pe) * F2 + (f0 + pf)) * PPLANE + p) * 16);
        float4 v0 = g4[0], v1 = g4[1], v2 = g4[2], v3 = g4[3];
        uint4 q0, q1;
        q0.x = pk2(v0.x, v0.y); q0.y = pk2(v0.z, v0.w);
        q0.z = pk2(v1.x, v1.y); q0.w = pk2(v1.z, v1.w);
        q1.x = pk2(v2.x, v2.y); q1.y = pk2(v2.z, v2.w);
        q1.z = pk2(v3.x, v3.y); q1.w = pk2(v3.z, v3.w);
        *(uint4*)(sInB + swz(i * 32)) = q0;
        *(uint4*)(sInB + swz(i * 32 + 16)) = q1;
    }
    __syncthreads();

    int l = tid & 63, wv = tid >> 6;
    int co = l & 15, kh = l >> 4;
    int tapsel = (l >> 5) & 1;         // which tap of the pair this lane reads
    int halfsel = (kh & 1) * 16;       // ci-half byte offset

    float bv = bias[co];
    f32x4 acc0 = {bv, bv, bv, bv}, acc1 = acc0, acc2 = acc0;

    // A-fragment base byte offset for tile t, this lane (row = l&15)
    auto mkbase = [&](int t) -> int {
        int n = t * 16 + (l & 15);
        if (n >= 324) n = 0;
        int le = n / 162;
        int rem = n - le * 162;
        int lf = rem / 81;
        int s = rem - lf * 81;
        int g = s / 9, h = s - g * 9;
        return ((le * 4 + lf) * PPLANE + g * H2 + h) * 32 + halfsel;
    };
    int base0 = mkbase(wv);
    int base1 = mkbase(wv + 8);
    int base2 = mkbase(wv + 16);
    bool has2 = (wv + 16) < 21;        // waves 5..7 only do 2 tiles (wave-uniform)

    const short8* wpv = (const short8*)wp;

    #pragma unroll
    for (int pair = 0; pair < NPAIR; ++pair) {
        const int t0 = pair * 2;
        const int t1 = (pair * 2 + 1 < 81) ? pair * 2 + 1 : 80;  // addr dup; weights are 0
        const int off0 = (((t0 / 27) * 4 + (t0 / 9) % 3) * PPLANE + ((t0 / 3) % 3) * H2 + t0 % 3) * 32;
        const int off1 = (((t1 / 27) * 4 + (t1 / 9) % 3) * PPLANE + ((t1 / 3) % 3) * H2 + t1 % 3) * 32;
        int toff = tapsel ? off1 : off0;

        short8 bfrag = wpv[pair * 64 + l];   // global, L2-resident
        short8 a0 = *(const short8*)(sInB + swz(base0 + toff));
        acc0 = __builtin_amdgcn_mfma_f32_16x16x32_bf16(a0, bfrag, acc0, 0, 0, 0);
        short8 a1 = *(const short8*)(sInB + swz(base1 + toff));
        acc1 = __builtin_amdgcn_mfma_f32_16x16x32_bf16(a1, bfrag, acc1, 0, 0, 0);
        if (has2) {
            short8 a2 = *(const short8*)(sInB + swz(base2 + toff));
            acc2 = __builtin_amdgcn_mfma_f32_16x16x32_bf16(a2, bfrag, acc2, 0, 0, 0);
        }
    }

    // ---- store: C/D mapping col=lane&15 (co), row=(lane>>4)*4+reg ----
    float* gout = out + (size_t)b * PPOS * 16;
    auto store_tile = [&](const f32x4& a, int t) {
        #pragma unroll
        for (int reg = 0; reg < 4; ++reg) {
            int row = kh * 4 + reg;
            int n = t * 16 + row;
            if (n < 324) {
                int le = n / 162;
                int rem = n - le * 162;
                int lf = rem / 81;
                int s = rem - lf * 81;
                int g = s / 9, h = s - g * 9;
                int gpos = ((e0 + le + 1) * F2 + (f0 + lf + 1)) * PPLANE + (g + 1) * H2 + (h + 1);
                gout[(size_t)gpos * 16 + co] = fmaxf(a[reg], 0.f);
            }
        }
    };
    store_tile(acc0, wv);
    store_tile(acc1, wv + 8);
    if (has2) store_tile(acc2, wv + 16);
}

// ---------------- feat = mean over (e,f): [b][c][81] ----------------
__global__ void feat_kernel(const float* __restrict__ a, float* __restrict__ feat, int nb) {
    int idx = blockIdx.x * 256 + threadIdx.x;
    if (idx >= nb * CH * 81) return;
    int s = idx % 81;
    int c = (idx / 81) % CH;
    int b = idx / (81 * CH);
    int g = s / 9, h = s % 9;
    const float* ap = a + (size_t)b * PPOS * 16 + ((g + 1) * H2 + (h + 1)) * 16 + c;
    float sum = 0.f;
    #pragma unroll
    for (int e = 0; e < 10; ++e)
        #pragma unroll
        for (int f = 0; f < 10; ++f)
            sum += ap[(size_t)(((e + 1) * F2 + (f + 1)) * PPLANE) * 16];
    feat[idx] = sum * 0.01f;
}

// ---------------- fc ----------------
__global__ void fc_kernel(const float* __restrict__ feat, const float* __restrict__ fcw,
                          const float* __restrict__ fcb, float* __restrict__ out, int nb) {
    int idx = blockIdx.x * 256 + threadIdx.x;
    if (idx >= nb * OUTC * 81) return;
    int s = idx % 81;
    int o = (idx / 81) % OUTC;
    int b = idx / (81 * OUTC);
    const float* fp = feat + (size_t)b * CH * 81 + s;
    float acc = fcb[o];
    #pragma unroll
    for (int c = 0; c < CH; ++c) acc += fcw[o * CH + c] * fp[c * 81];
    out[idx] = acc;
}

extern "C" void kernel_launch(void* const* d_in, const int* in_sizes, int n_in,
                              void* d_out, int out_size, void* d_ws, size_t ws_size,
                              hipStream_t stream) {
    const float* x   = (const float*)d_in[0];
    const float* w1  = (const float*)d_in[1];
    const float* b1  = (const float*)d_in[2];
    const float* w2  = (const float*)d_in[3];
    const float* b2  = (const float*)d_in[4];
    const float* w3  = (const float*)d_in[5];
    const float* b3  = (const float*)d_in[6];
    const float* w4  = (const float*)d_in[7];
    const float* b4  = (const float*)d_in[8];
    const float* w5  = (const float*)d_in[9];
    const float* b5  = (const float*)d_in[10];
    const float* fcw = (const float*)d_in[11];
    const float* fcb = (const float*)d_in[12];
    float* outp = (float*)d_out;

    // ---- ws layout ----
    char* wsc = (char*)d_ws;
    const size_t wp_bytes = 4ull * WPL * sizeof(ushort_t);     // 167936 B
    uint4* wp_all = (uint4*)wsc;
    size_t off = wp_bytes;

    const size_t perb_bytes = (size_t)PPOS * (1 + 16 + 16) * 4 + (size_t)CH * 81 * 4;
    size_t avail = (ws_size > off) ? ws_size - off : 0;
    int nbmax = (int)(avail / perb_bytes);
    if (nbmax < 1) nbmax = 1;
    if (nbmax > BB) nbmax = BB;

    float* featb = (float*)(wsc + off);  off += (size_t)nbmax * CH * 81 * 4;
    float* bufP  = (float*)(wsc + off);  off += (size_t)nbmax * PPOS * 4;
    float* bufA  = (float*)(wsc + off);  off += (size_t)nbmax * PPOS * 16 * 4;
    float* bufB  = (float*)(wsc + off);

    // ---- pack weights for L2..L5 ----
    const float* ws_[4] = {w2, w3, w4, w5};
    for (int i = 0; i < 4; ++i)
        pack_w_kernel<<<(NPAIR * 64 + 255) / 256, 256, 0, stream>>>(
            ws_[i], wp_all + (size_t)i * (NPAIR * 64));

    // ---- zero padded buffers (pads must be 0; interiors are overwritten) ----
    hipMemsetAsync(bufP, 0, (size_t)nbmax * PPOS * (1 + 32) * 4, stream);

    for (int b0 = 0; b0 < BB; b0 += nbmax) {
        int nb = BB - b0;
        if (nb > nbmax) nb = nbmax;

        int pt = nb * NBANDS * 81;
        prep_kernel<<<(pt + 255) / 256, 256, 0, stream>>>(x + (size_t)b0 * NBANDS * 81, bufP, nb);

        dim3 c1g(4, 2, nb);
        conv1_kernel<<<c1g, 256, 0, stream>>>(bufP, w1, b1, bufA);

        dim3 mg(25, nb);
        conv_mfma_kernel<<<mg, 512, 0, stream>>>(bufA, wp_all + 0 * (NPAIR * 64), b2, bufB);
        conv_mfma_kernel<<<mg, 512, 0, stream>>>(bufB, wp_all + 1 * (NPAIR * 64), b3, bufA);
        conv_mfma_kernel<<<mg, 512, 0, stream>>>(bufA, wp_all + 2 * (NPAIR * 64), b4, bufB);
        conv_mfma_kernel<<<mg, 512, 0, stream>>>(bufB, wp_all + 3 * (NPAIR * 64), b5, bufA);

        int ft = nb * CH * 81;
        feat_kernel<<<(ft + 255) / 256, 256, 0, stream>>>(bufA, featb, nb);

        int ot = nb * OUTC * 81;
        fc_kernel<<<(ot + 255) / 256, 256, 0, stream>>>(featb, fcw, fcb, outp + (size_t)b0 * OUTC * 81, nb);
    }
}